// Round 13
// baseline (1301.750 us; speedup 1.0000x reference)
//
#include <hip/hip_runtime.h>
#include <math.h>

typedef _Float16 h8 __attribute__((ext_vector_type(8)));
typedef _Float16 h2 __attribute__((ext_vector_type(2)));
typedef float f32x4 __attribute__((ext_vector_type(4)));

__device__ __forceinline__ float clampf(float x, float lo, float hi) {
    return fminf(fmaxf(x, lo), hi);
}

__global__ void zero_ints(int* __restrict__ p, int n) {
    int i = blockIdx.x * 256 + threadIdx.x;
    if (i < n) p[i] = 0;
}

// fp16 B-frag repack for CIN=64 layers, permuted k' layout (see round 9).
__global__ void repack_wh(const float* __restrict__ cw, const float* __restrict__ fw,
                          _Float16* __restrict__ Wh, int COUT, int COTILES) {
    int idx = blockIdx.x * 256 + threadIdx.x;
    int total = COTILES * 130 * 512;
    if (idx >= total) return;
    int j = idx & 7;
    int l = (idx >> 3) & 63;
    int rest = idx >> 9;
    int s = rest % 130;
    int t = rest / 130;
    int kp = s * 32 + (l >> 4) * 8 + j;
    int co = t * 16 + (l & 15);
    float v = 0.f;
    if (co < COUT) {
        if (kp < 4096) {
            int rowi = kp >> 9;
            int ivd = (kp >> 7) & 3;
            int c = (kp >> 1) & 63;
            int slot = kp & 1;
            int iv = ivd * 2 + slot;
            v = cw[((rowi * 8 + iv) * 64 + c) * COUT + co];
        } else {
            v = fw[(kp - 4096) * COUT + co];
        }
    }
    Wh[idx] = (_Float16)v;
}

__global__ void edge_hist(const int* __restrict__ ei, const int* __restrict__ ej,
                          int* __restrict__ counts, int E) {
    int e = blockIdx.x * 256 + threadIdx.x;
    if (e >= E) return;
    int i = ei[e], j = ej[e];
    if (i != j) atomicAdd(&counts[i], 1);
}

__global__ __launch_bounds__(1024) void scan_kernel(const int* __restrict__ counts,
                                                    int* __restrict__ offs,
                                                    int* __restrict__ cursor, int N) {
    __shared__ int sums[1024];
    const int t = threadIdx.x;
    const int per = (N + 1023) / 1024;
    const int lo = t * per;
    const int hi = min(lo + per, N);
    int s = 0;
    for (int i = lo; i < hi; ++i) s += counts[i];
    sums[t] = s;
    __syncthreads();
    for (int d = 1; d < 1024; d <<= 1) {
        int v = (t >= d) ? sums[t - d] : 0;
        __syncthreads();
        sums[t] += v;
        __syncthreads();
    }
    int run = (t > 0) ? sums[t - 1] : 0;
    for (int i = lo; i < hi; ++i) {
        offs[i] = run;
        cursor[i] = run;
        run += counts[i];
    }
    if (t == 1023) offs[N] = sums[1023];
}

// ---- degree-balanced node permutation (counting sort by degree) ----
__global__ void deg_hist(const int* __restrict__ counts, int* __restrict__ dhist, int N) {
    int n = blockIdx.x * 256 + threadIdx.x;
    if (n >= N) return;
    atomicAdd(&dhist[min(counts[n], 511)], 1);
}

__global__ __launch_bounds__(512) void deg_scan(const int* __restrict__ dhist,
                                                int* __restrict__ dcur) {
    __shared__ int s[512];
    int t = threadIdx.x;
    s[t] = dhist[t];
    __syncthreads();
    for (int d = 1; d < 512; d <<= 1) {
        int v = (t >= d) ? s[t - d] : 0;
        __syncthreads();
        s[t] += v;
        __syncthreads();
    }
    dcur[t] = (t > 0) ? s[t - 1] : 0;
}

// perm descending by degree: heaviest blocks dispatch first (kills grid tail)
__global__ void deg_scatter(const int* __restrict__ counts, int* __restrict__ dcur,
                            int* __restrict__ perm, int N) {
    int n = blockIdx.x * 256 + threadIdx.x;
    if (n >= N) return;
    int p = atomicAdd(&dcur[min(counts[n], 511)], 1);
    perm[N - 1 - p] = n;
}

// csr_all[e] = uint4:
//   .x = j[0:17) | r0>>1 [17:19) | r1>>1 [19:21) | iv [21:24)
//   .y = o0[0:11) | o1[11:22) | odd[22]   (o0/o1 = r*256+ivd*64, h2 units)
//   .z = fp16x2 {wu0*gv, wu0*fv}  (even u-row r0)
//   .w = fp16x2 {wu1*gv, wu1*fv}  (odd  u-row r1)
__global__ void edge_scatter(const int* __restrict__ ei, const int* __restrict__ ej,
                             const float* __restrict__ pos, int* __restrict__ cursor,
                             uint4* __restrict__ csr_all, int E) {
    int e = blockIdx.x * 256 + threadIdx.x;
    if (e >= E) return;
    int i = ei[e], j = ej[e];
    if (i == j) return;
    float dx = clampf(pos[i * 2 + 0] - pos[j * 2 + 0], -1.f, 1.f);
    float dy = clampf(pos[i * 2 + 1] - pos[j * 2 + 1], -1.f, 1.f);
    float r = sqrtf(dx * dx + dy * dy + 1e-12f);
    float u = clampf(2.f * r - 1.f, -1.f, 1.f);
    float v = atan2f(dy, dx) * 0.3183098861837907f;  // / pi
    float tu = (u + 1.f) * 3.5f;
    float tv = (v + 1.f) * 3.5f;
    int iu = min(6, max(0, (int)floorf(tu)));
    int iv = min(6, max(0, (int)floorf(tv)));
    float fu = clampf(tu - (float)iu, 0.f, 1.f);
    float fv = clampf(tv - (float)iv, 0.f, 1.f);
    bool even = (iu & 1) == 0;
    int rowi0 = even ? iu : iu + 1;  // even u-row
    int rowi1 = even ? iu + 1 : iu;  // odd u-row
    float wu0 = even ? (1.f - fu) : fu;
    float wu1 = even ? fu : (1.f - fu);
    float gv = 1.f - fv;
    int ivd = iv >> 1;
    unsigned o0 = (unsigned)(rowi0 * 256 + ivd * 64);
    unsigned o1 = (unsigned)(rowi1 * 256 + ivd * 64);
    unsigned offp = o0 | (o1 << 11) | ((unsigned)(iv & 1) << 22);
    unsigned a0 = (unsigned)__builtin_bit_cast(unsigned short, (_Float16)(wu0 * gv)) |
                  ((unsigned)__builtin_bit_cast(unsigned short, (_Float16)(wu0 * fv)) << 16);
    unsigned a1 = (unsigned)__builtin_bit_cast(unsigned short, (_Float16)(wu1 * gv)) |
                  ((unsigned)__builtin_bit_cast(unsigned short, (_Float16)(wu1 * fv)) << 16);
    int p = atomicAdd(&cursor[i], 1);
    csr_all[p] = make_uint4(
        (unsigned)j | ((unsigned)(rowi0 >> 1) << 17) | ((unsigned)(rowi1 >> 1) << 19) |
            ((unsigned)iv << 21),
        offp, a0, a1);
}

// ---------------------------------------------------------------------------
// Layers 1..2 (CIN=64, COUT=64). 16 waves = 16 nodes (degree-matched via
// perm), fp16 moments, one wave per node, all 4 taps, plain RMW (no ds
// atomics: 3x slower, round 6). Batch 8 edges in flight. 133 KB LDS.
// GEMM: 16-way K-split, direct fp16 A-frags, f16 MFMA, LDS partial-reduce.
// MODE 1: relu in, out = conv(+dense row) + cb + fb ; MODE 2: + residual x
template <int MODE>
__global__ __launch_bounds__(1024, 4) void conv64_mfma(
    const float* __restrict__ x, const _Float16* __restrict__ Wh,
    const float* __restrict__ cb, const float* __restrict__ fb,
    const int* __restrict__ offs, const uint4* __restrict__ csr_all,
    const int* __restrict__ perm, float* __restrict__ out, int nNodes) {
    constexpr int TM = 16;
    constexpr int KSTEPS = 130;
    constexpr int RSH = 4168;       // halfs per node row (8336 B)
    constexpr int RSD = RSH / 2;    // h2 per row
    extern __shared__ float mom[];  // 133376 B
    const int tid = threadIdx.x;
    const int w = tid >> 6;
    const int lane = tid & 63;
    const int base = blockIdx.x * TM;
    const int idx = base + w;
    const int n = (idx < nNodes) ? perm[idx] : -1;

    {  // zero moments
        float4 z = make_float4(0.f, 0.f, 0.f, 0.f);
        float4* m4 = (float4*)mom;
        for (int i = tid; i < TM * RSH / 8; i += 1024) m4[i] = z;
    }
    __syncthreads();

    // ---- scatter
    if (n >= 0) {
        const int e0 = offs[n], e1 = offs[n + 1];
        h2* momn2 = (h2*)mom + w * RSD;
        const int c = lane;
        for (int b = e0; b < e1; b += 8) {
            uint4 ca[8];
            float xv[8];
#pragma unroll
            for (int u = 0; u < 8; ++u) {
                int e = b + u;
                bool ok = e < e1;
                ca[u] = csr_all[ok ? e : e0];
                xv[u] = ok ? 1.f : 0.f;
            }
#pragma unroll
            for (int u = 0; u < 8; ++u) {
                int j = ca[u].x & 0x1FFFF;
                xv[u] *= fmaxf(x[j * 64 + c], 0.f);
            }
#pragma unroll
            for (int u = 0; u < 8; ++u) {
                int o0 = ca[u].y & 0x7FF;
                int o1 = (ca[u].y >> 11) & 0x7FF;
                _Float16 xh = (_Float16)xv[u];
                h2 xh2 = {xh, xh};
                h2 v0 = xh2 * __builtin_bit_cast(h2, ca[u].z);
                h2 v1 = xh2 * __builtin_bit_cast(h2, ca[u].w);
                h2* bp0 = momn2 + o0 + c;
                h2* bp1 = momn2 + o1 + c;
                if (!(ca[u].y >> 22)) {  // wave-uniform branch
                    bp0[0] += v0;
                    bp1[0] += v1;
                } else {
                    unsigned u0 = __builtin_bit_cast(unsigned, v0);
                    unsigned u1 = __builtin_bit_cast(unsigned, v1);
                    bp0[0] += __builtin_bit_cast(h2, u0 << 16);
                    bp0[64] += __builtin_bit_cast(h2, u0 >> 16);
                    bp1[0] += __builtin_bit_cast(h2, u1 << 16);
                    bp1[64] += __builtin_bit_cast(h2, u1 >> 16);
                }
            }
        }
        // dense row k' = 4096 + lane
        ((_Float16*)mom)[w * RSH + 4096 + lane] = (_Float16)fmaxf(x[n * 64 + lane], 0.f);
    }

    // ---- GEMM: K-chunk for this wave (130 = 2*9 + 14*8)
    const int s0 = w * 8 + min(w, 2);
    const int s_end = s0 + 8 + (w < 2 ? 1 : 0);
    const int quad = lane >> 4;
    const _Float16* arow = (const _Float16*)mom + (lane & 15) * RSH;

    const uint4* Bp = (const uint4*)Wh;
    uint4 b0[4], b1[4];
#pragma unroll
    for (int t = 0; t < 4; ++t) {  // prefetch before barrier
        b0[t] = Bp[((size_t)t * KSTEPS + s0) * 64 + lane];
        b1[t] = Bp[((size_t)t * KSTEPS + s0 + 1) * 64 + lane];
    }
    __syncthreads();
    f32x4 acc[4] = {{0, 0, 0, 0}, {0, 0, 0, 0}, {0, 0, 0, 0}, {0, 0, 0, 0}};
    for (int s = s0; s < s_end; ++s) {
        uint4 bq[4];
#pragma unroll
        for (int t = 0; t < 4; ++t) {
            bq[t] = b0[t];
            b0[t] = b1[t];
            if (s + 2 < s_end) b1[t] = Bp[((size_t)t * KSTEPS + s + 2) * 64 + lane];
        }
        h8 a = *(const h8*)(arow + s * 32 + quad * 8);
#pragma unroll
        for (int t = 0; t < 4; ++t)
            acc[t] = __builtin_amdgcn_mfma_f32_16x16x32_f16(a, __builtin_bit_cast(h8, bq[t]),
                                                            acc[t], 0, 0, 0);
    }
    __syncthreads();  // moments dead -> reuse as reduce scratch
    f32x4* red = (f32x4*)mom;
#pragma unroll
    for (int t = 0; t < 4; ++t) red[(w * 4 + t) * 64 + lane] = acc[t];
    __syncthreads();
    if (w < 4) {
        f32x4 s = {0, 0, 0, 0};
#pragma unroll
        for (int g = 0; g < 16; ++g) s += red[(g * 4 + w) * 64 + lane];
        const int co = w * 16 + (lane & 15);
#pragma unroll
        for (int i = 0; i < 4; ++i) {
            int ridx = base + quad * 4 + i;
            if (ridx < nNodes) {
                int nn = perm[ridx];
                float res = s[i] + cb[co] + fb[co];
                if (MODE == 2) res += x[nn * 64 + co];
                out[nn * 64 + co] = res;
            }
        }
    }
}

// ---------------------------------------------------------------------------
// Layer 3 (CIN=64, COUT=2): direct per-edge form, W3 (32 KB) in LDS,
// fp32 register accumulation, butterfly reduce. One wave per (perm) node.
__global__ __launch_bounds__(1024, 4) void conv_last(
    const float* __restrict__ x, const float* __restrict__ cw3, const float* __restrict__ fw3,
    const float* __restrict__ cb3, const float* __restrict__ fb3,
    const int* __restrict__ offs, const uint4* __restrict__ csr_all,
    const int* __restrict__ perm, float* __restrict__ out, int nNodes) {
    constexpr int TM = 16;
    __shared__ float2 W2[4096];  // 32 KB
    __shared__ float2 FW2[64];
    const int tid = threadIdx.x;
    const int w = tid >> 6;
    const int lane = tid & 63;
    const int base = blockIdx.x * TM;
    const int idx = base + w;
    const int n = (idx < nNodes) ? perm[idx] : -1;

    {  // stage weights
        const float2* src = (const float2*)cw3;
        for (int d = tid; d < 4096; d += 1024) W2[d] = src[d];
        if (tid < 64) FW2[tid] = ((const float2*)fw3)[tid];
    }
    __syncthreads();

    float2 acc = make_float2(0.f, 0.f);
    if (n >= 0) {
        const int e0 = offs[n], e1 = offs[n + 1];
        const int c = lane;
        for (int b = e0; b < e1; b += 8) {
            uint4 ca[8];
            float xv[8];
#pragma unroll
            for (int u = 0; u < 8; ++u) {
                int e = b + u;
                bool ok = e < e1;
                ca[u] = csr_all[ok ? e : e0];
                xv[u] = ok ? 1.f : 0.f;
            }
#pragma unroll
            for (int u = 0; u < 8; ++u) {
                int j = ca[u].x & 0x1FFFF;
                xv[u] *= fmaxf(x[j * 64 + c], 0.f);
            }
#pragma unroll
            for (int u = 0; u < 8; ++u) {
                int r0 = ((ca[u].x >> 17) & 3) << 1;
                int r1 = (((ca[u].x >> 19) & 3) << 1) + 1;
                int iv = (ca[u].x >> 21) & 7;
                h2 wh0 = __builtin_bit_cast(h2, ca[u].z);
                h2 wh1 = __builtin_bit_cast(h2, ca[u].w);
                float w00 = (float)wh0[0], w01 = (float)wh0[1];
                float w10 = (float)wh1[0], w11 = (float)wh1[1];
                int b00 = (r0 * 8 + iv) * 64 + c;
                int b10 = (r1 * 8 + iv) * 64 + c;
                float2 t00 = W2[b00], t01 = W2[b00 + 64];
                float2 t10 = W2[b10], t11 = W2[b10 + 64];
                float wsx = w00 * t00.x + w01 * t01.x + w10 * t10.x + w11 * t11.x;
                float wsy = w00 * t00.y + w01 * t01.y + w10 * t10.y + w11 * t11.y;
                acc.x += xv[u] * wsx;
                acc.y += xv[u] * wsy;
            }
        }
        float xr = fmaxf(x[n * 64 + lane], 0.f);
        float2 fwp = FW2[lane];
        acc.x += xr * fwp.x;
        acc.y += xr * fwp.y;
    }
#pragma unroll
    for (int d = 1; d < 64; d <<= 1) {
        acc.x += __shfl_xor(acc.x, d);
        acc.y += __shfl_xor(acc.y, d);
    }
    if (lane == 0 && n >= 0) {
        out[n * 2 + 0] = (acc.x + cb3[0] + fb3[0]) * (1.f / 128.f);
        out[n * 2 + 1] = (acc.y + cb3[1] + fb3[1]) * (1.f / 128.f);
    }
}

// ---------------------------------------------------------------------------
// Layer 0 (CIN=4, no relu): direct per-edge form, one wave per (perm) node.
__global__ __launch_bounds__(1024, 4) void conv0_direct(
    const float* __restrict__ x, const float* __restrict__ cw0, const float* __restrict__ fw0,
    const float* __restrict__ cb0, const float* __restrict__ fb0,
    const int* __restrict__ offs, const uint4* __restrict__ csr_all,
    const int* __restrict__ perm, float* __restrict__ out, int nNodes) {
    constexpr int TM = 16;
    __shared__ float2 W0p[4096];  // 32 KB
    __shared__ float2 FW0p[64];
    const int tid = threadIdx.x;
    const int w = tid >> 6;
    const int lane = tid & 63;
    const int base = blockIdx.x * TM;
    const int idx = base + w;
    const int n = (idx < nNodes) ? perm[idx] : -1;

    {  // stage W0 permuted: [bin][h][co] float2(c=2h, 2h+1)
        for (int d = tid; d < 4096; d += 1024) {
            int co = d & 31;
            int h = (d >> 5) & 1;
            int bin = d >> 6;
            W0p[d] = make_float2(cw0[(bin * 4 + 2 * h) * 32 + co],
                                 cw0[(bin * 4 + 2 * h + 1) * 32 + co]);
        }
        if (tid < 64) {
            int co = tid & 31;
            int h = tid >> 5;
            FW0p[tid] = make_float2(fw0[(2 * h) * 32 + co], fw0[(2 * h + 1) * 32 + co]);
        }
    }
    __syncthreads();

    const int co = lane & 31;
    const int h = lane >> 5;
    float accC = 0.f, accL = 0.f;
    if (n >= 0) {
        const int e0 = offs[n], e1 = offs[n + 1];
        for (int b = e0; b < e1; b += 8) {
            uint4 ca[8];
            float xc0[8], xc1[8];
#pragma unroll
            for (int u = 0; u < 8; ++u) {
                int e = b + u;
                bool ok = e < e1;
                ca[u] = csr_all[ok ? e : e0];
                xc0[u] = ok ? 1.f : 0.f;
            }
#pragma unroll
            for (int u = 0; u < 8; ++u) {
                int j = ca[u].x & 0x1FFFF;
                const float4 xj = *(const float4*)(x + j * 4);  // no relu (layer 0)
                float a = h ? xj.z : xj.x;
                float bb = h ? xj.w : xj.y;
                xc1[u] = xc0[u] * bb;
                xc0[u] = xc0[u] * a;
            }
#pragma unroll
            for (int u = 0; u < 8; ++u) {
                int r0 = ((ca[u].x >> 17) & 3) << 1;
                int r1 = (((ca[u].x >> 19) & 3) << 1) + 1;
                int iv = (ca[u].x >> 21) & 7;
                h2 wh0 = __builtin_bit_cast(h2, ca[u].z);
                h2 wh1 = __builtin_bit_cast(h2, ca[u].w);
                float w00 = (float)wh0[0], w01 = (float)wh0[1];
                float w10 = (float)wh1[0], w11 = (float)wh1[1];
                int i00 = ((r0 * 8 + iv) * 2 + h) * 32 + co;
                int i10 = ((r1 * 8 + iv) * 2 + h) * 32 + co;
                float2 t00 = W0p[i00], t01 = W0p[i00 + 64];
                float2 t10 = W0p[i10], t11 = W0p[i10 + 64];
                accC += w00 * (xc0[u] * t00.x + xc1[u] * t00.y);
                accC += w01 * (xc0[u] * t01.x + xc1[u] * t01.y);
                accC += w10 * (xc0[u] * t10.x + xc1[u] * t10.y);
                accC += w11 * (xc0[u] * t11.x + xc1[u] * t11.y);
            }
        }
        const float4 xn = *(const float4*)(x + n * 4);
        float a = h ? xn.z : xn.x;
        float bb = h ? xn.w : xn.y;
        float2 fwp = FW0p[h * 32 + co];
        accL = a * fwp.x + bb * fwp.y;
    }
    accC += __shfl_xor(accC, 32);
    accL += __shfl_xor(accL, 32);
    if (lane < 32 && n >= 0) {
        out[n * 64 + co] = accL + fb0[co];
        out[n * 64 + 32 + co] = accC + cb0[co];
    }
}

extern "C" void kernel_launch(void* const* d_in, const int* in_sizes, int n_in,
                              void* d_out, int out_size, void* d_ws, size_t ws_size,
                              hipStream_t stream) {
    const float* pos = (const float*)d_in[0];
    const float* feat = (const float*)d_in[1];
    const int* ei = (const int*)d_in[2];
    const int* ej = (const int*)d_in[3];
    const float* cw0 = (const float*)d_in[4];
    const float* cb0 = (const float*)d_in[5];
    const float* fw0 = (const float*)d_in[6];
    const float* fb0 = (const float*)d_in[7];
    const float* cw1 = (const float*)d_in[8];
    const float* cb1 = (const float*)d_in[9];
    const float* fw1 = (const float*)d_in[10];
    const float* fb1 = (const float*)d_in[11];
    const float* cw2 = (const float*)d_in[12];
    const float* cb2 = (const float*)d_in[13];
    const float* fw2 = (const float*)d_in[14];
    const float* fb2 = (const float*)d_in[15];
    const float* cw3 = (const float*)d_in[16];
    const float* cb3 = (const float*)d_in[17];
    const float* fw3 = (const float*)d_in[18];
    const float* fb3 = (const float*)d_in[19];
    float* outp = (float*)d_out;

    const int N = in_sizes[0] / 2;
    const int E = in_sizes[2];

    char* wsp = (char*)d_ws;
    size_t off = 0;
    auto alloc = [&](size_t bytes) -> void* {
        void* p = wsp + off;
        off = (off + bytes + 255) & ~(size_t)255;
        return p;
    };
    int* counts = (int*)alloc((size_t)(N + 512) * 4);  // counts[N] + dhist[512]
    int* dhist = counts + N;
    int* offs = (int*)alloc((size_t)(N + 1) * 4);
    int* cursor = (int*)alloc((size_t)N * 4);
    int* dcur = (int*)alloc((size_t)512 * 4);
    int* perm = (int*)alloc((size_t)N * 4);
    uint4* csr_all = (uint4*)alloc((size_t)E * 16);
    float* ansA = (float*)alloc((size_t)N * 64 * 4);
    float* ansB = (float*)alloc((size_t)N * 64 * 4);
    _Float16* Wh1 = (_Float16*)alloc((size_t)4 * 130 * 512 * 2);
    _Float16* Wh2 = (_Float16*)alloc((size_t)4 * 130 * 512 * 2);
    (void)ws_size;
    (void)n_in;
    (void)out_size;

    const int BIG_LDS = 16 * 4168 * 2;  // 133376 B
    hipFuncSetAttribute((const void*)&conv64_mfma<1>,
                        hipFuncAttributeMaxDynamicSharedMemorySize, BIG_LDS);
    hipFuncSetAttribute((const void*)&conv64_mfma<2>,
                        hipFuncAttributeMaxDynamicSharedMemorySize, BIG_LDS);

    zero_ints<<<dim3((N + 512 + 255) / 256), dim3(256), 0, stream>>>(counts, N + 512);
    repack_wh<<<dim3((4 * 130 * 512 + 255) / 256), dim3(256), 0, stream>>>(cw1, fw1, Wh1, 64, 4);
    repack_wh<<<dim3((4 * 130 * 512 + 255) / 256), dim3(256), 0, stream>>>(cw2, fw2, Wh2, 64, 4);
    edge_hist<<<dim3((E + 255) / 256), dim3(256), 0, stream>>>(ei, ej, counts, E);
    scan_kernel<<<dim3(1), dim3(1024), 0, stream>>>(counts, offs, cursor, N);
    deg_hist<<<dim3((N + 255) / 256), dim3(256), 0, stream>>>(counts, dhist, N);
    deg_scan<<<dim3(1), dim3(512), 0, stream>>>(dhist, dcur);
    deg_scatter<<<dim3((N + 255) / 256), dim3(256), 0, stream>>>(counts, dcur, perm, N);
    edge_scatter<<<dim3((E + 255) / 256), dim3(256), 0, stream>>>(ei, ej, pos, cursor, csr_all, E);

    const int nb = (N + 15) / 16;
    conv0_direct<<<dim3(nb), dim3(1024), 0, stream>>>(
        feat, cw0, fw0, cb0, fb0, offs, csr_all, perm, ansA, N);
    conv64_mfma<1><<<dim3(nb), dim3(1024), BIG_LDS, stream>>>(
        ansA, Wh1, cb1, fb1, offs, csr_all, perm, ansB, N);
    conv64_mfma<2><<<dim3(nb), dim3(1024), BIG_LDS, stream>>>(
        ansB, Wh2, cb2, fb2, offs, csr_all, perm, ansA, N);
    conv_last<<<dim3(nb), dim3(1024), 0, stream>>>(
        ansA, cw3, fw3, cb3, fb3, offs, csr_all, perm, outp, N);
}